// Round 1
// baseline (126.475 us; speedup 1.0000x reference)
//
#include <hip/hip_runtime.h>

// HashGridPositionalEncoding4D:
//   B=8, N=131072, NUM_LEVELS=16, LEVEL_DIM=2, TABLE_SIZE=65536, D_MODEL=32
//   idx[l] = (u32(fmod(c0*f,2^32)) ^ u32(fmod((c1*f)*P1,2^32)) ^ ...) & 0xFFFF
//   out = x + tables[l, idx[l]] interleaved (l,d) -> feature f = 2*l+d
//
// Mapping: 8 lanes per point. Lane slot j handles output floats [4j,4j+4) =
// levels 2j and 2j+1. x/out accesses are lane-contiguous float4 (fully
// coalesced); coords float4 is shared by 8 lanes (L1 broadcast); each lane
// does two random 8B gathers from the 8MB table set (L2/LLC resident).

#define NPOINTS (8 * 131072)
#define TABLE_MASK 65535u

__global__ __launch_bounds__(256) void hashgrid4d_kernel(
    const float* __restrict__ x,
    const float* __restrict__ coords,
    const float* __restrict__ tables,
    const float* __restrict__ freq_bands,
    float* __restrict__ out)
{
    const int gid  = blockIdx.x * blockDim.x + threadIdx.x;  // (point, slot)
    const int p    = gid >> 3;
    const int slot = gid & 7;

    // coords for this point (8 lanes share; hardware broadcasts)
    const float4 c4 = *reinterpret_cast<const float4*>(coords + (size_t)p * 4);
    const float c0 = fminf(fmaxf(c4.x, 0.0f), 1.0f);
    const float c1 = fminf(fmaxf(c4.y, 0.0f), 1.0f);
    const float c2 = fminf(fmaxf(c4.z, 0.0f), 1.0f);
    const float c3 = fminf(fmaxf(c4.w, 0.0f), 1.0f);

    // PRIMES as float32 (compiler rounds these literals to nearest f32,
    // identical to np.array([...], dtype=np.float32))
    const float P1 = 2654435761.0f;
    const float P2 = 805459861.0f;
    const float P3 = 3674653429.0f;

    float enc[4];

    #pragma unroll
    for (int j = 0; j < 2; ++j) {
        const int l = slot * 2 + j;
        const float f = freq_bands[l];

        // v = (c * freq) * prime  -- two separate f32 multiplies, no FMA,
        // no reassociation: matches JAX/numpy left-associated broadcast.
        const float t0 = __fmul_rn(c0, f);
        const float t1 = __fmul_rn(c1, f);
        const float t2 = __fmul_rn(c2, f);
        const float t3 = __fmul_rn(c3, f);

        // jnp.mod(v, 2^32).astype(uint32) for v>=0  ==  (u32)((u64)v)
        // (fmod is exact; truncation commutes with the 2^32 wrap)
        const unsigned int h0 = (unsigned int)(unsigned long long)t0;  // prime = 1
        const unsigned int h1 = (unsigned int)(unsigned long long)__fmul_rn(t1, P1);
        const unsigned int h2 = (unsigned int)(unsigned long long)__fmul_rn(t2, P2);
        const unsigned int h3 = (unsigned int)(unsigned long long)__fmul_rn(t3, P3);

        const unsigned int idx = (h0 ^ h1 ^ h2 ^ h3) & TABLE_MASK;

        const float2 ft = *reinterpret_cast<const float2*>(
            tables + (((size_t)l << 16) + idx) * 2);
        enc[2 * j]     = ft.x;
        enc[2 * j + 1] = ft.y;
    }

    const size_t off = (size_t)gid * 4;
    const float4 xv = *reinterpret_cast<const float4*>(x + off);
    float4 o;
    o.x = xv.x + enc[0];
    o.y = xv.y + enc[1];
    o.z = xv.z + enc[2];
    o.w = xv.w + enc[3];
    *reinterpret_cast<float4*>(out + off) = o;
}

extern "C" void kernel_launch(void* const* d_in, const int* in_sizes, int n_in,
                              void* d_out, int out_size, void* d_ws, size_t ws_size,
                              hipStream_t stream) {
    const float* x          = (const float*)d_in[0];
    const float* coords     = (const float*)d_in[1];
    const float* tables     = (const float*)d_in[2];
    const float* freq_bands = (const float*)d_in[3];
    float* out              = (float*)d_out;

    const int total_threads = NPOINTS * 8;       // 8,388,608
    const int block = 256;
    const int grid  = total_threads / block;     // 32,768

    hashgrid4d_kernel<<<grid, block, 0, stream>>>(x, coords, tables, freq_bands, out);
}

// Round 3
// 126.298 us; speedup vs baseline: 1.0014x; 1.0014x over previous
//
#include <hip/hip_runtime.h>

// HashGridPositionalEncoding4D — ILP=4 variant (round 2: fix nontemporal
// builtin types — needs native ext_vector, not HIP_vector_type).
//   B=8, N=131072, NUM_LEVELS=16, LEVEL_DIM=2, TABLE_SIZE=65536, D_MODEL=32
//
// Mapping: 8 lane-slots per point; lane slot j produces output floats
// [4j,4j+4) = levels 2j,2j+1. Each thread processes ILP=4 items strided by
// TOTAL/4, so consecutive lanes stay consecutive (float4 x/out fully
// coalesced) and `slot` is identical across the 4 items (freq regs shared).
//
// Rationale (round 1 counters): latency-bound, not BW-bound (1.4 TB/s fetch,
// VALU 12%). 4 independent chains per thread quadruple outstanding gather
// misses. x/out use non-temporal hints so the 268 MB stream doesn't evict
// the 8 MB table set from per-XCD L2.

#define NPOINTS (8 * 131072)
#define TOTAL_ITEMS (NPOINTS * 8)      // 8,388,608
#define ILP 4
#define STRIDE (TOTAL_ITEMS / ILP)     // 2,097,152
#define TABLE_MASK 65535u

typedef float v4f __attribute__((ext_vector_type(4)));
typedef float v2f __attribute__((ext_vector_type(2)));

__global__ __launch_bounds__(256) void hashgrid4d_kernel(
    const float* __restrict__ x,
    const float* __restrict__ coords,
    const float* __restrict__ tables,
    const float* __restrict__ freq_bands,
    float* __restrict__ out)
{
    const int tid  = blockIdx.x * blockDim.x + threadIdx.x;
    const int slot = tid & 7;          // same for all ILP items (STRIDE % 8 == 0)

    const float f0 = freq_bands[slot * 2 + 0];
    const float f1 = freq_bands[slot * 2 + 1];

    // PRIMES rounded to float32, identical to np.array(..., dtype=np.float32)
    const float P1 = 2654435761.0f;
    const float P2 = 805459861.0f;
    const float P3 = 3674653429.0f;

    // ---- 1) issue all coords loads (independent) ----
    v4f c[ILP];
    #pragma unroll
    for (int k = 0; k < ILP; ++k) {
        const int p = (tid + k * STRIDE) >> 3;
        c[k] = *reinterpret_cast<const v4f*>(coords + (size_t)p * 4);
    }

    // ---- 2) hash + issue all 8 gathers ----
    v2f ft[ILP][2];
    #pragma unroll
    for (int k = 0; k < ILP; ++k) {
        const float c0 = fminf(fmaxf(c[k].x, 0.0f), 1.0f);
        const float c1 = fminf(fmaxf(c[k].y, 0.0f), 1.0f);
        const float c2 = fminf(fmaxf(c[k].z, 0.0f), 1.0f);
        const float c3 = fminf(fmaxf(c[k].w, 0.0f), 1.0f);
        #pragma unroll
        for (int j = 0; j < 2; ++j) {
            const float f = j ? f1 : f0;
            const int   l = slot * 2 + j;
            // v = (c*f)*P — two separate rn-multiplies, no FMA/reassoc (exact
            // match to the JAX/numpy broadcast). mod 2^32 + astype(uint32) of a
            // non-negative float == trunc-to-u64 then wrap to u32 (fmod exact).
            const float t0 = __fmul_rn(c0, f);
            const float t1 = __fmul_rn(c1, f);
            const float t2 = __fmul_rn(c2, f);
            const float t3 = __fmul_rn(c3, f);
            const unsigned int h0 = (unsigned int)(unsigned long long)t0;
            const unsigned int h1 = (unsigned int)(unsigned long long)__fmul_rn(t1, P1);
            const unsigned int h2 = (unsigned int)(unsigned long long)__fmul_rn(t2, P2);
            const unsigned int h3 = (unsigned int)(unsigned long long)__fmul_rn(t3, P3);
            const unsigned int idx = (h0 ^ h1 ^ h2 ^ h3) & TABLE_MASK;
            ft[k][j] = *reinterpret_cast<const v2f*>(
                tables + (((size_t)l << 16) + idx) * 2);
        }
    }

    // ---- 3) issue all x loads (non-temporal: streamed once) ----
    v4f xv[ILP];
    #pragma unroll
    for (int k = 0; k < ILP; ++k) {
        const size_t off = (size_t)(tid + k * STRIDE) * 4;
        xv[k] = __builtin_nontemporal_load(
            reinterpret_cast<const v4f*>(x + off));
    }

    // ---- 4) add + non-temporal stores ----
    #pragma unroll
    for (int k = 0; k < ILP; ++k) {
        const size_t off = (size_t)(tid + k * STRIDE) * 4;
        v4f o;
        o.x = xv[k].x + ft[k][0].x;
        o.y = xv[k].y + ft[k][0].y;
        o.z = xv[k].z + ft[k][1].x;
        o.w = xv[k].w + ft[k][1].y;
        __builtin_nontemporal_store(o, reinterpret_cast<v4f*>(out + off));
    }
}

extern "C" void kernel_launch(void* const* d_in, const int* in_sizes, int n_in,
                              void* d_out, int out_size, void* d_ws, size_t ws_size,
                              hipStream_t stream) {
    const float* x          = (const float*)d_in[0];
    const float* coords     = (const float*)d_in[1];
    const float* tables     = (const float*)d_in[2];
    const float* freq_bands = (const float*)d_in[3];
    float* out              = (float*)d_out;

    const int block = 256;
    const int grid  = STRIDE / block;  // 8192 blocks, each thread does ILP=4 items

    hashgrid4d_kernel<<<grid, block, 0, stream>>>(x, coords, tables, freq_bands, out);
}